// Round 1
// baseline (6878.929 us; speedup 1.0000x reference)
//
#include <hip/hip_runtime.h>
#include <hip/hip_bf16.h>
#include <stdint.h>

#define B_  256
#define T_  128
#define E_  256
#define H_  512
#define G4  2048
#define U1_ 256
#define U2_ 64

#define NWG 128   // recurrent workgroups; each owns MS=4 hidden indices (16 z-rows gate-grouped)
#define MS  4

typedef __attribute__((ext_vector_type(8))) short bf16x8;
typedef __attribute__((ext_vector_type(4))) float f32x4;

static __device__ __forceinline__ unsigned short f2bf(float f) {
    unsigned u = __float_as_uint(f);
    unsigned r = (u + 0x7FFFu + ((u >> 16) & 1u)) >> 16;   // RNE
    return (unsigned short)r;
}

// ---------------- A1: gather embeddings -> xb[t][b][e] (bf16) ----------------
__global__ __launch_bounds__(256) void k_gather(const int* __restrict__ inp,
                                                const float* __restrict__ emb,
                                                short* __restrict__ xb) {
    const int tid = threadIdx.x;
    const int lr  = tid >> 5;          // 0..7 (row within iter-chunk)
    const int e0  = (tid & 31) * 8;    // 8 elems per thread
    for (int it = 0; it < 16; ++it) {
        int row = (blockIdx.x * 16 + it) * 8 + lr;     // 0..32767 == t*256+b
        int t = row >> 8, b = row & 255;
        int idx = inp[b * T_ + t];
        const float* src = emb + (long)idx * E_ + e0;
        float4 v0 = *(const float4*)src;
        float4 v1 = *(const float4*)(src + 4);
        bf16x8 o;
        o[0]=(short)f2bf(v0.x); o[1]=(short)f2bf(v0.y); o[2]=(short)f2bf(v0.z); o[3]=(short)f2bf(v0.w);
        o[4]=(short)f2bf(v1.x); o[5]=(short)f2bf(v1.y); o[6]=(short)f2bf(v1.z); o[7]=(short)f2bf(v1.w);
        *(bf16x8*)(xb + (long)row * E_ + e0) = o;
    }
}

// ---------------- B: persistent recurrent kernel ----------------
__global__ __launch_bounds__(256, 1) void k_lstm(
    const float* __restrict__ U,      // [H_][G4]
    const float* __restrict__ W,      // [E_][G4]
    const float* __restrict__ bias,   // [G4]
    const short* __restrict__ xb,     // [T_][B_][E_] bf16
    short* hx,                        // [2][B_][H_] bf16 (double buffer)
    unsigned int* cnt,                // [T_] arrival counters
    float* hfin)                      // [B_][H_] f32
{
    const int tid  = threadIdx.x;
    const int wid  = blockIdx.x;        // 0..NWG-1
    const int m0   = wid * MS;
    const int lane = tid & 63;
    const int wv   = tid >> 6;          // wave 0..3 -> batch slice
    const int c16  = lane & 15;
    const int g4   = lane >> 4;         // k-block selector; also gate group on C/D rows

    // A-frag row r = c16 -> j = gate(r)*H + m0 + (r&3)
    const int jA = ((c16 >> 2) * H_) + m0 + (c16 & 3);

    // Prologue: pack U/W slices into persistent MFMA A-fragments (registers).
    bf16x8 a_u[16];
    #pragma unroll
    for (int kc = 0; kc < 16; ++kc) {
        int kbase = kc * 32 + g4 * 8;
        bf16x8 a;
        #pragma unroll
        for (int e = 0; e < 8; ++e) a[e] = (short)f2bf(U[(long)(kbase + e) * G4 + jA]);
        a_u[kc] = a;
    }
    bf16x8 a_w[8];
    #pragma unroll
    for (int kc = 0; kc < 8; ++kc) {
        int kbase = kc * 32 + g4 * 8;
        bf16x8 a;
        #pragma unroll
        for (int e = 0; e < 8; ++e) a[e] = (short)f2bf(W[(long)(kbase + e) * G4 + jA]);
        a_w[kc] = a;
    }
    // bias for C/D reg q: row = g4*4+q -> gate g4, m = m0+q
    float bq[4];
    #pragma unroll
    for (int q = 0; q < 4; ++q) bq[q] = bias[g4 * H_ + m0 + q];

    const int bw = wv * 64;             // this wave's batch base
    float cst[4][4];                    // cell state c[q][n] (redundant across lane groups)
    #pragma unroll
    for (int q = 0; q < 4; ++q)
        #pragma unroll
        for (int n = 0; n < 4; ++n) cst[q][n] = 0.f;

    for (int t = 0; t < T_; ++t) {
        if (t > 0) {
            if (tid == 0) {
                unsigned iter = 0;
                while (__hip_atomic_load(&cnt[t - 1], __ATOMIC_RELAXED,
                                         __HIP_MEMORY_SCOPE_AGENT) < NWG) {
                    __builtin_amdgcn_s_sleep(8);
                    if (++iter > (1u << 20)) break;   // safety: fail loud, not hang
                }
            }
            __syncthreads();
            __builtin_amdgcn_fence(__ATOMIC_ACQUIRE, "agent");
        }
        const short* hr = hx + (long)((t & 1) ^ 1) * (B_ * H_);
        const short* xr = xb + (long)t * (B_ * E_);

        f32x4 acc[4];
        #pragma unroll
        for (int n = 0; n < 4; ++n) acc[n] = (f32x4){bq[0], bq[1], bq[2], bq[3]};

        // z += U^T(slice) @ h^T   (K = 512)
        #pragma unroll 4
        for (int kc = 0; kc < 16; ++kc) {
            int kb = kc * 32 + g4 * 8;
            #pragma unroll
            for (int n = 0; n < 4; ++n) {
                bf16x8 bfr = *(const bf16x8*)(hr + (long)(bw + n * 16 + c16) * H_ + kb);
                acc[n] = __builtin_amdgcn_mfma_f32_16x16x32_bf16(a_u[kc], bfr, acc[n], 0, 0, 0);
            }
        }
        // z += W^T(slice) @ x_t^T (K = 256)
        #pragma unroll 4
        for (int kc = 0; kc < 8; ++kc) {
            int kb = kc * 32 + g4 * 8;
            #pragma unroll
            for (int n = 0; n < 4; ++n) {
                bf16x8 bfr = *(const bf16x8*)(xr + (long)(bw + n * 16 + c16) * E_ + kb);
                acc[n] = __builtin_amdgcn_mfma_f32_16x16x32_bf16(a_w[kc], bfr, acc[n], 0, 0, 0);
            }
        }

        // Gates: lane group g4 owns gate g4 (rows g4*4+q). Apply own activation, then
        // shuffle activated values so every lane gets (i,f,g,o) for (q, col).
        float hval[4][4];
        #pragma unroll
        for (int n = 0; n < 4; ++n) {
            #pragma unroll
            for (int q = 0; q < 4; ++q) {
                float z = acc[n][q];
                float a = (g4 == 2) ? fmaxf(z, 0.f)               // candidate gate: relu
                                    : 1.f / (1.f + __expf(-z));   // i,f,o: sigmoid
                float ai = __shfl(a, c16,      64);
                float af = __shfl(a, c16 + 16, 64);
                float ag = __shfl(a, c16 + 32, 64);
                float ao = __shfl(a, c16 + 48, 64);
                float c_ = af * cst[q][n] + ai * ag;
                cst[q][n] = c_;
                hval[q][n] = ao * fmaxf(c_, 0.f);
            }
        }

        if (t < T_ - 1) {
            short* hw = hx + (long)(t & 1) * (B_ * H_);
            if (lane < 16) {      // group 0 publishes (values identical in all groups)
                #pragma unroll
                for (int n = 0; n < 4; ++n) {
                    ushort4 pk;
                    pk.x = f2bf(hval[0][n]); pk.y = f2bf(hval[1][n]);
                    pk.z = f2bf(hval[2][n]); pk.w = f2bf(hval[3][n]);
                    *(ushort4*)(hw + (long)(bw + n * 16 + lane) * H_ + m0) = pk;
                }
            }
            __syncthreads();      // drains each wave's stores (vmcnt) before barrier
            if (tid == 0) {
                __builtin_amdgcn_fence(__ATOMIC_RELEASE, "agent");   // wbl2: flush to L3
                __hip_atomic_fetch_add(&cnt[t], 1u, __ATOMIC_RELAXED,
                                       __HIP_MEMORY_SCOPE_AGENT);
            }
        } else {
            if (lane < 16) {
                #pragma unroll
                for (int n = 0; n < 4; ++n) {
                    float4 pk = make_float4(hval[0][n], hval[1][n], hval[2][n], hval[3][n]);
                    *(float4*)(hfin + (long)(bw + n * 16 + lane) * H_ + m0) = pk;
                }
            }
        }
    }
}

// ---------------- C: dense head + softmax ----------------
__global__ __launch_bounds__(256) void k_head(const float* __restrict__ hfin,
                                              const float* __restrict__ W2,
                                              const float* __restrict__ b2,
                                              const float* __restrict__ W3,
                                              const float* __restrict__ b3,
                                              float* __restrict__ out) {
    __shared__ float hs[H_];
    __shared__ float ys[U1_];
    __shared__ float ps[4][U2_];
    const int b = blockIdx.x, tid = threadIdx.x;
    if (tid < 128) *(float4*)(hs + tid * 4) = *(const float4*)(hfin + (long)b * H_ + tid * 4);
    __syncthreads();
    float acc = b2[tid];
    #pragma unroll 8
    for (int k = 0; k < H_; ++k) acc += hs[k] * W2[(long)k * U1_ + tid];
    ys[tid] = fmaxf(acc, 0.f);
    __syncthreads();
    const int u2 = tid & 63, part = tid >> 6;
    float p = 0.f;
    #pragma unroll 8
    for (int k = part * 64; k < part * 64 + 64; ++k) p += ys[k] * W3[(long)k * U2_ + u2];
    ps[part][u2] = p;
    __syncthreads();
    if (tid < 64) {
        float lg = b3[tid] + ps[0][tid] + ps[1][tid] + ps[2][tid] + ps[3][tid];
        float m = lg;
        #pragma unroll
        for (int off = 32; off >= 1; off >>= 1) m = fmaxf(m, __shfl_xor(m, off, 64));
        float e = __expf(lg - m);
        float s = e;
        #pragma unroll
        for (int off = 32; off >= 1; off >>= 1) s += __shfl_xor(s, off, 64);
        out[(long)b * U2_ + tid] = e / s;
    }
}

extern "C" void kernel_launch(void* const* d_in, const int* in_sizes, int n_in,
                              void* d_out, int out_size, void* d_ws, size_t ws_size,
                              hipStream_t stream) {
    const int*   inp = (const int*)d_in[0];
    const float* emb = (const float*)d_in[1];
    const float* W   = (const float*)d_in[2];
    const float* U   = (const float*)d_in[3];
    const float* bb  = (const float*)d_in[4];
    const float* W2  = (const float*)d_in[5];
    const float* b2  = (const float*)d_in[6];
    const float* W3  = (const float*)d_in[7];
    const float* b3  = (const float*)d_in[8];

    char* ws = (char*)d_ws;
    short*        hx   = (short*)ws;                                   // 2 * 256 KiB
    unsigned int* cnt  = (unsigned int*)(ws + 524288);                 // 512 B (pad 4K)
    short*        xb   = (short*)(ws + (1 << 20));                     // 16 MiB
    float*        hfin = (float*)(ws + (1 << 20) + (long)T_ * B_ * E_ * 2);  // 512 KiB

    // zero h(-1) double-buffer + per-step counters (replay-deterministic)
    hipMemsetAsync(ws, 0, 524288 + 4096, stream);
    k_gather<<<256, 256, 0, stream>>>(inp, emb, xb);
    k_lstm<<<NWG, 256, 0, stream>>>(U, W, bb, xb, hx, cnt, hfin);
    k_head<<<B_, 256, 0, stream>>>(hfin, W2, b2, W3, b3, (float*)d_out);
}

// Round 2
// 6161.500 us; speedup vs baseline: 1.1164x; 1.1164x over previous
//
#include <hip/hip_runtime.h>
#include <hip/hip_bf16.h>
#include <stdint.h>

#define B_  256
#define T_  128
#define E_  256
#define H_  512
#define G4  2048
#define U1_ 256
#define U2_ 64

#define NWG 128   // recurrent workgroups; each owns MS=4 hidden indices (16 z-rows gate-grouped)
#define MS  4

typedef __attribute__((ext_vector_type(8))) short bf16x8;
typedef __attribute__((ext_vector_type(4))) float f32x4;
typedef unsigned long long ull;

static __device__ __forceinline__ unsigned short f2bf(float f) {
    unsigned u = __float_as_uint(f);
    unsigned r = (u + 0x7FFFu + ((u >> 16) & 1u)) >> 16;   // RNE
    return (unsigned short)r;
}

// ---------------- A1: gather embeddings -> xb[t][b][e] (bf16) ----------------
__global__ __launch_bounds__(256) void k_gather(const int* __restrict__ inp,
                                                const float* __restrict__ emb,
                                                short* __restrict__ xb) {
    const int tid = threadIdx.x;
    const int lr  = tid >> 5;          // 0..7 (row within iter-chunk)
    const int e0  = (tid & 31) * 8;    // 8 elems per thread
    for (int it = 0; it < 16; ++it) {
        int row = (blockIdx.x * 16 + it) * 8 + lr;     // 0..32767 == t*256+b
        int t = row >> 8, b = row & 255;
        int idx = inp[b * T_ + t];
        const float* src = emb + (long)idx * E_ + e0;
        float4 v0 = *(const float4*)src;
        float4 v1 = *(const float4*)(src + 4);
        bf16x8 o;
        o[0]=(short)f2bf(v0.x); o[1]=(short)f2bf(v0.y); o[2]=(short)f2bf(v0.z); o[3]=(short)f2bf(v0.w);
        o[4]=(short)f2bf(v1.x); o[5]=(short)f2bf(v1.y); o[6]=(short)f2bf(v1.z); o[7]=(short)f2bf(v1.w);
        *(bf16x8*)(xb + (long)row * E_ + e0) = o;
    }
}

// ---------------- B: persistent recurrent kernel ----------------
// Sync scheme (no atomics RMW, no release fences):
//   - h published with relaxed AGENT-scope 8B atomic stores (sc1 -> L3 direct,
//     local L2 never dirty -> no buffer_wbl2 needed).
//   - __syncthreads() drains vmcnt for all waves, then tid0 stores its per-WG
//     flag (agent store, own 16B slot -> no shared-line RMW contention).
//   - consumers: thread i polls flag[i] (own slot), ballot-free (each spins on
//     its own), then barrier + acquire fence (buffer_inv) + cached h loads.
__global__ __launch_bounds__(256, 1) void k_lstm(
    const float* __restrict__ U,      // [H_][G4]
    const float* __restrict__ W,      // [E_][G4]
    const float* __restrict__ bias,   // [G4]
    const short* __restrict__ xb,     // [T_][B_][E_] bf16
    short* hx,                        // [2][B_][H_] bf16 (double buffer)
    unsigned int* flags,              // [NWG*4] per-WG step flags (16B spaced)
    float* hfin)                      // [B_][H_] f32
{
    const int tid  = threadIdx.x;
    const int wid  = blockIdx.x;        // 0..NWG-1
    const int m0   = wid * MS;
    const int lane = tid & 63;
    const int wv   = tid >> 6;          // wave 0..3 -> batch slice
    const int c16  = lane & 15;
    const int g4   = lane >> 4;         // k-block selector; also gate group on C/D rows

    // A-frag row r = c16 -> j = gate(r)*H + m0 + (r&3)
    const int jA = ((c16 >> 2) * H_) + m0 + (c16 & 3);

    // Prologue: pack U/W slices into persistent MFMA A-fragments (registers).
    bf16x8 a_u[16];
    #pragma unroll
    for (int kc = 0; kc < 16; ++kc) {
        int kbase = kc * 32 + g4 * 8;
        bf16x8 a;
        #pragma unroll
        for (int e = 0; e < 8; ++e) a[e] = (short)f2bf(U[(long)(kbase + e) * G4 + jA]);
        a_u[kc] = a;
    }
    bf16x8 a_w[8];
    #pragma unroll
    for (int kc = 0; kc < 8; ++kc) {
        int kbase = kc * 32 + g4 * 8;
        bf16x8 a;
        #pragma unroll
        for (int e = 0; e < 8; ++e) a[e] = (short)f2bf(W[(long)(kbase + e) * G4 + jA]);
        a_w[kc] = a;
    }
    // bias for C/D reg q: row = g4*4+q -> gate g4, m = m0+q
    float bq[4];
    #pragma unroll
    for (int q = 0; q < 4; ++q) bq[q] = bias[g4 * H_ + m0 + q];

    const int bw = wv * 64;             // this wave's batch base
    float cst[4][4];                    // cell state c[q][n] (redundant across lane groups)
    #pragma unroll
    for (int q = 0; q < 4; ++q)
        #pragma unroll
        for (int n = 0; n < 4; ++n) cst[q][n] = 0.f;

    for (int t = 0; t < T_; ++t) {
        const short* xr = xb + (long)t * (B_ * E_);

        // Prefetch x B-frags for n=0,1 BEFORE the wait: x is h-independent, so
        // these loads fly during the spin. Registers survive buffer_inv.
        bf16x8 xp[2][8];
        #pragma unroll
        for (int kc = 0; kc < 8; ++kc) {
            #pragma unroll
            for (int n = 0; n < 2; ++n)
                xp[n][kc] = *(const bf16x8*)(xr + (long)(bw + n * 16 + c16) * E_ + kc * 32 + g4 * 8);
        }

        if (t > 0) {
            if (tid < NWG) {
                unsigned iter = 0;
                while (__hip_atomic_load(&flags[tid * 4], __ATOMIC_RELAXED,
                                         __HIP_MEMORY_SCOPE_AGENT) < (unsigned)t) {
                    __builtin_amdgcn_s_sleep(2);
                    if (++iter > (1u << 22)) break;   // fail loud, never hang
                }
            }
            __syncthreads();
            __builtin_amdgcn_fence(__ATOMIC_ACQUIRE, "agent");   // buffer_inv: L1/L2
        }
        const short* hr = hx + (long)((t & 1) ^ 1) * (B_ * H_);

        f32x4 acc[4];
        #pragma unroll
        for (int n = 0; n < 4; ++n) acc[n] = (f32x4){bq[0], bq[1], bq[2], bq[3]};

        // z += U^T(slice) @ h^T   (K = 512)
        #pragma unroll 4
        for (int kc = 0; kc < 16; ++kc) {
            int kb = kc * 32 + g4 * 8;
            #pragma unroll
            for (int n = 0; n < 4; ++n) {
                bf16x8 bfr = *(const bf16x8*)(hr + (long)(bw + n * 16 + c16) * H_ + kb);
                acc[n] = __builtin_amdgcn_mfma_f32_16x16x32_bf16(a_u[kc], bfr, acc[n], 0, 0, 0);
            }
        }
        // z += W^T(slice) @ x_t^T (K = 256); n=0,1 from prefetch regs
        #pragma unroll 4
        for (int kc = 0; kc < 8; ++kc) {
            int kb = kc * 32 + g4 * 8;
            acc[0] = __builtin_amdgcn_mfma_f32_16x16x32_bf16(a_w[kc], xp[0][kc], acc[0], 0, 0, 0);
            acc[1] = __builtin_amdgcn_mfma_f32_16x16x32_bf16(a_w[kc], xp[1][kc], acc[1], 0, 0, 0);
            #pragma unroll
            for (int n = 2; n < 4; ++n) {
                bf16x8 bfr = *(const bf16x8*)(xr + (long)(bw + n * 16 + c16) * E_ + kb);
                acc[n] = __builtin_amdgcn_mfma_f32_16x16x32_bf16(a_w[kc], bfr, acc[n], 0, 0, 0);
            }
        }

        // Gates: lane group g4 owns gate g4 (rows g4*4+q). Apply own activation, then
        // shuffle activated values so every lane gets (i,f,g,o) for (q, col).
        float hval[4][4];
        #pragma unroll
        for (int n = 0; n < 4; ++n) {
            #pragma unroll
            for (int q = 0; q < 4; ++q) {
                float z = acc[n][q];
                float a = (g4 == 2) ? fmaxf(z, 0.f)               // candidate gate: relu
                                    : 1.f / (1.f + __expf(-z));   // i,f,o: sigmoid
                float ai = __shfl(a, c16,      64);
                float af = __shfl(a, c16 + 16, 64);
                float ag = __shfl(a, c16 + 32, 64);
                float ao = __shfl(a, c16 + 48, 64);
                float c_ = af * cst[q][n] + ai * ag;
                cst[q][n] = c_;
                hval[q][n] = ao * fmaxf(c_, 0.f);
            }
        }

        if (t < T_ - 1) {
            short* hw = hx + (long)(t & 1) * (B_ * H_);
            if (lane < 16) {      // group 0 publishes (values identical in all groups)
                #pragma unroll
                for (int n = 0; n < 4; ++n) {
                    ull pk =  (ull)f2bf(hval[0][n])
                           | ((ull)f2bf(hval[1][n]) << 16)
                           | ((ull)f2bf(hval[2][n]) << 32)
                           | ((ull)f2bf(hval[3][n]) << 48);
                    __hip_atomic_store((ull*)(hw + (long)(bw + n * 16 + lane) * H_ + m0),
                                       pk, __ATOMIC_RELAXED, __HIP_MEMORY_SCOPE_AGENT);
                }
            }
            __syncthreads();      // drains vmcnt for ALL waves' h-stores, then barrier
            if (tid == 0) {
                __hip_atomic_store(&flags[wid * 4], (unsigned)(t + 1),
                                   __ATOMIC_RELAXED, __HIP_MEMORY_SCOPE_AGENT);
            }
        } else {
            if (lane < 16) {
                #pragma unroll
                for (int n = 0; n < 4; ++n) {
                    float4 pk = make_float4(hval[0][n], hval[1][n], hval[2][n], hval[3][n]);
                    *(float4*)(hfin + (long)(bw + n * 16 + lane) * H_ + m0) = pk;
                }
            }
        }
    }
}

// ---------------- C: dense head + softmax ----------------
__global__ __launch_bounds__(256) void k_head(const float* __restrict__ hfin,
                                              const float* __restrict__ W2,
                                              const float* __restrict__ b2,
                                              const float* __restrict__ W3,
                                              const float* __restrict__ b3,
                                              float* __restrict__ out) {
    __shared__ float hs[H_];
    __shared__ float ys[U1_];
    __shared__ float ps[4][U2_];
    const int b = blockIdx.x, tid = threadIdx.x;
    if (tid < 128) *(float4*)(hs + tid * 4) = *(const float4*)(hfin + (long)b * H_ + tid * 4);
    __syncthreads();
    float acc = b2[tid];
    #pragma unroll 8
    for (int k = 0; k < H_; ++k) acc += hs[k] * W2[(long)k * U1_ + tid];
    ys[tid] = fmaxf(acc, 0.f);
    __syncthreads();
    const int u2 = tid & 63, part = tid >> 6;
    float p = 0.f;
    #pragma unroll 8
    for (int k = part * 64; k < part * 64 + 64; ++k) p += ys[k] * W3[(long)k * U2_ + u2];
    ps[part][u2] = p;
    __syncthreads();
    if (tid < 64) {
        float lg = b3[tid] + ps[0][tid] + ps[1][tid] + ps[2][tid] + ps[3][tid];
        float m = lg;
        #pragma unroll
        for (int off = 32; off >= 1; off >>= 1) m = fmaxf(m, __shfl_xor(m, off, 64));
        float e = __expf(lg - m);
        float s = e;
        #pragma unroll
        for (int off = 32; off >= 1; off >>= 1) s += __shfl_xor(s, off, 64);
        out[(long)b * U2_ + tid] = e / s;
    }
}

extern "C" void kernel_launch(void* const* d_in, const int* in_sizes, int n_in,
                              void* d_out, int out_size, void* d_ws, size_t ws_size,
                              hipStream_t stream) {
    const int*   inp = (const int*)d_in[0];
    const float* emb = (const float*)d_in[1];
    const float* W   = (const float*)d_in[2];
    const float* U   = (const float*)d_in[3];
    const float* bb  = (const float*)d_in[4];
    const float* W2  = (const float*)d_in[5];
    const float* b2  = (const float*)d_in[6];
    const float* W3  = (const float*)d_in[7];
    const float* b3  = (const float*)d_in[8];

    char* ws = (char*)d_ws;
    short*        hx   = (short*)ws;                                   // 2 * 256 KiB
    unsigned int* flags= (unsigned int*)(ws + 524288);                 // 2 KiB (pad 4K)
    short*        xb   = (short*)(ws + (1 << 20));                     // 16 MiB
    float*        hfin = (float*)(ws + (1 << 20) + (long)T_ * B_ * E_ * 2);  // 512 KiB

    // zero h(-1) double-buffer + per-WG flags (replay-deterministic)
    hipMemsetAsync(ws, 0, 524288 + 4096, stream);
    k_gather<<<256, 256, 0, stream>>>(inp, emb, xb);
    k_lstm<<<NWG, 256, 0, stream>>>(U, W, bb, xb, hx, flags, hfin);
    k_head<<<B_, 256, 0, stream>>>(hfin, W2, b2, W3, b3, (float*)d_out);
}

// Round 3
// 1651.624 us; speedup vs baseline: 4.1649x; 3.7306x over previous
//
#include <hip/hip_runtime.h>
#include <hip/hip_bf16.h>
#include <stdint.h>

#define B_  256
#define T_  128
#define E_  256
#define H_  512
#define G4  2048
#define U1_ 256
#define U2_ 64

#define NWG 128   // recurrent workgroups; each owns MS=4 hidden indices (16 z-rows gate-grouped)
#define MS  4

// h fragment buffer: [btile(16)][kc(16)][lane(64)][e(8)] bf16 = 256 KB per buffer
#define HFRAG_SHORTS (16 * 16 * 64 * 8)
// x fragment buffer per step: [btile(16)][kc(8)][lane(64)][e(8)] bf16 = 128 KB
#define XFRAG_SHORTS (16 * 8 * 64 * 8)

typedef __attribute__((ext_vector_type(8))) short bf16x8;
typedef __attribute__((ext_vector_type(4))) float f32x4;
typedef unsigned long long ull;

static __device__ __forceinline__ unsigned short f2bf(float f) {
    unsigned u = __float_as_uint(f);
    unsigned r = (u + 0x7FFFu + ((u >> 16) & 1u)) >> 16;   // RNE
    return (unsigned short)r;
}

// ---------- A1: gather embeddings -> x in MFMA B-frag layout (bf16) ----------
// B-frag for (btile, kc): lane l holds x[btile*16 + (l&15)][kc*32 + (l>>4)*8 + e]
__global__ __launch_bounds__(256) void k_gather(const int* __restrict__ inp,
                                                const float* __restrict__ emb,
                                                short* __restrict__ xfrag) {
    const int tid  = threadIdx.x;
    const int wv   = tid >> 6;
    const int lane = tid & 63;
    const int c16  = lane & 15;
    const int g4   = lane >> 4;
    for (int it = 0; it < 16; ++it) {
        int task  = (it * 256 + blockIdx.x) * 4 + wv;   // 0..16383 = t*128 + btile*8 + kc
        int kc    = task & 7;
        int btile = (task >> 3) & 15;
        int t     = task >> 7;
        int b     = btile * 16 + c16;
        int idx   = inp[b * T_ + t];
        const float* src = emb + (long)idx * E_ + kc * 32 + g4 * 8;
        float4 v0 = *(const float4*)src;
        float4 v1 = *(const float4*)(src + 4);
        bf16x8 o;
        o[0]=(short)f2bf(v0.x); o[1]=(short)f2bf(v0.y); o[2]=(short)f2bf(v0.z); o[3]=(short)f2bf(v0.w);
        o[4]=(short)f2bf(v1.x); o[5]=(short)f2bf(v1.y); o[6]=(short)f2bf(v1.z); o[7]=(short)f2bf(v1.w);
        // coalesced: 64 lanes write 1KB contiguous
        *(bf16x8*)(xfrag + ((long)((t * 16 + btile) * 8 + kc) * 64 + lane) * 8) = o;
    }
}

// ---------------- B: persistent recurrent kernel ----------------
// h double-buffered in B-frag layout; published with relaxed agent-scope 8B
// stores (write-through, no wbl2 fence needed); per-WG flags signal steps;
// consumers poll own flag slot, then acquire-fence (buffer_inv) + coalesced
// frag loads (lane*16B contiguous).
__global__ __launch_bounds__(256, 1) void k_lstm(
    const float* __restrict__ U,      // [H_][G4]
    const float* __restrict__ W,      // [E_][G4]
    const float* __restrict__ bias,   // [G4]
    const short* __restrict__ xfrag,  // [T_][16][8][64][8] bf16
    short* hfrag,                     // [2][16][16][64][8] bf16 (double buffer)
    unsigned int* flags,              // [NWG*4] per-WG step flags (16B spaced)
    float* hfin)                      // [B_][H_] f32
{
    const int tid  = threadIdx.x;
    const int wid  = blockIdx.x;        // 0..NWG-1
    const int m0   = wid * MS;
    const int lane = tid & 63;
    const int wv   = tid >> 6;          // wave 0..3 -> batch slice
    const int c16  = lane & 15;
    const int g4   = lane >> 4;         // k-subblock; C/D gate group; publish n-block

    // A-frag row r = c16 -> j = gate(r)*H + m0 + (r&3)
    const int jA = ((c16 >> 2) * H_) + m0 + (c16 & 3);

    // Prologue: pack U/W slices into persistent MFMA A-fragments (registers).
    bf16x8 a_u[16];
    #pragma unroll
    for (int kc = 0; kc < 16; ++kc) {
        int kbase = kc * 32 + g4 * 8;
        bf16x8 a;
        #pragma unroll
        for (int e = 0; e < 8; ++e) a[e] = (short)f2bf(U[(long)(kbase + e) * G4 + jA]);
        a_u[kc] = a;
    }
    bf16x8 a_w[8];
    #pragma unroll
    for (int kc = 0; kc < 8; ++kc) {
        int kbase = kc * 32 + g4 * 8;
        bf16x8 a;
        #pragma unroll
        for (int e = 0; e < 8; ++e) a[e] = (short)f2bf(W[(long)(kbase + e) * G4 + jA]);
        a_w[kc] = a;
    }
    float bq[4];
    #pragma unroll
    for (int q = 0; q < 4; ++q) bq[q] = bias[g4 * H_ + m0 + q];

    const int bw = wv * 64;             // this wave's batch base
    float cst[4][4];                    // cell state c[q][n] (redundant across lane groups)
    #pragma unroll
    for (int q = 0; q < 4; ++q)
        #pragma unroll
        for (int n = 0; n < 4; ++n) cst[q][n] = 0.f;

    // publish address components (constant per thread)
    const int kcw  = m0 >> 5;                         // h k-block of this WG
    const int lpos = ((m0 & 31) >> 3) * 16 + c16;     // lane slot within frag block
    const int e0   = m0 & 7;                          // element offset (0 or 4)

    for (int t = 0; t < T_; ++t) {
        const short* xr = xfrag + (long)t * XFRAG_SHORTS + lane * 8;

        // Prefetch x B-frags for n=0,1 BEFORE the wait (h-independent; regs
        // survive buffer_inv). Coalesced 1KB loads.
        bf16x8 xp[2][8];
        #pragma unroll
        for (int kc = 0; kc < 8; ++kc) {
            #pragma unroll
            for (int n = 0; n < 2; ++n)
                xp[n][kc] = *(const bf16x8*)(xr + (long)((wv * 4 + n) * 8 + kc) * 512);
        }

        if (t > 0) {
            if (tid < NWG) {
                unsigned iter = 0;
                while (__hip_atomic_load(&flags[tid * 4], __ATOMIC_RELAXED,
                                         __HIP_MEMORY_SCOPE_AGENT) < (unsigned)t) {
                    __builtin_amdgcn_s_sleep(2);
                    if (++iter > (1u << 22)) break;   // fail loud, never hang
                }
            }
            __syncthreads();
            __builtin_amdgcn_fence(__ATOMIC_ACQUIRE, "agent");   // buffer_inv
        }
        const short* hr = hfrag + (long)((t & 1) ^ 1) * HFRAG_SHORTS + lane * 8;

        f32x4 acc[4];
        #pragma unroll
        for (int n = 0; n < 4; ++n) acc[n] = (f32x4){bq[0], bq[1], bq[2], bq[3]};

        // z += U^T(slice) @ h^T   (K = 512) — coalesced frag loads
        #pragma unroll
        for (int kc = 0; kc < 16; ++kc) {
            #pragma unroll
            for (int n = 0; n < 4; ++n) {
                bf16x8 bfr = *(const bf16x8*)(hr + (long)((wv * 4 + n) * 16 + kc) * 512);
                acc[n] = __builtin_amdgcn_mfma_f32_16x16x32_bf16(a_u[kc], bfr, acc[n], 0, 0, 0);
            }
        }
        // z += W^T(slice) @ x_t^T (K = 256); n=0,1 from prefetch regs
        #pragma unroll
        for (int kc = 0; kc < 8; ++kc) {
            acc[0] = __builtin_amdgcn_mfma_f32_16x16x32_bf16(a_w[kc], xp[0][kc], acc[0], 0, 0, 0);
            acc[1] = __builtin_amdgcn_mfma_f32_16x16x32_bf16(a_w[kc], xp[1][kc], acc[1], 0, 0, 0);
            #pragma unroll
            for (int n = 2; n < 4; ++n) {
                bf16x8 bfr = *(const bf16x8*)(xr + (long)((wv * 4 + n) * 8 + kc) * 512);
                acc[n] = __builtin_amdgcn_mfma_f32_16x16x32_bf16(a_w[kc], bfr, acc[n], 0, 0, 0);
            }
        }

        // Gates: lane group g4 owns gate g4 (rows g4*4+q). Apply own activation,
        // shuffle so every lane gets (i,f,g,o) for (q, col c16) of every n.
        float hval[4][4];
        #pragma unroll
        for (int n = 0; n < 4; ++n) {
            #pragma unroll
            for (int q = 0; q < 4; ++q) {
                float z = acc[n][q];
                float a = (g4 == 2) ? fmaxf(z, 0.f)               // candidate: relu
                                    : 1.f / (1.f + __expf(-z));   // i,f,o: sigmoid
                float ai = __shfl(a, c16,      64);
                float af = __shfl(a, c16 + 16, 64);
                float ag = __shfl(a, c16 + 32, 64);
                float ao = __shfl(a, c16 + 48, 64);
                float c_ = af * cst[q][n] + ai * ag;
                cst[q][n] = c_;
                hval[q][n] = ao * fmaxf(c_, 0.f);
            }
        }

        if (t < T_ - 1) {
            // Publish into frag layout: group g4 publishes n-block g4.
            // Lane (c16,g4) -> batch b = bw + g4*16 + c16, hidden m0..m0+3.
            short* hw = hfrag + (long)(t & 1) * HFRAG_SHORTS;
            ull pk =  (ull)f2bf(hval[0][g4])
                   | ((ull)f2bf(hval[1][g4]) << 16)
                   | ((ull)f2bf(hval[2][g4]) << 32)
                   | ((ull)f2bf(hval[3][g4]) << 48);
            __hip_atomic_store(
                (ull*)(hw + (long)((wv * 4 + g4) * 16 + kcw) * 512 + lpos * 8 + e0),
                pk, __ATOMIC_RELAXED, __HIP_MEMORY_SCOPE_AGENT);
            __syncthreads();      // drains vmcnt for ALL waves' h-stores
            if (tid == 0) {
                __hip_atomic_store(&flags[wid * 4], (unsigned)(t + 1),
                                   __ATOMIC_RELAXED, __HIP_MEMORY_SCOPE_AGENT);
            }
        } else {
            if (lane < 16) {
                #pragma unroll
                for (int n = 0; n < 4; ++n) {
                    float4 pk = make_float4(hval[0][n], hval[1][n], hval[2][n], hval[3][n]);
                    *(float4*)(hfin + (long)(bw + n * 16 + lane) * H_ + m0) = pk;
                }
            }
        }
    }
}

// ---------------- C: dense head + softmax ----------------
__global__ __launch_bounds__(256) void k_head(const float* __restrict__ hfin,
                                              const float* __restrict__ W2,
                                              const float* __restrict__ b2,
                                              const float* __restrict__ W3,
                                              const float* __restrict__ b3,
                                              float* __restrict__ out) {
    __shared__ float hs[H_];
    __shared__ float ys[U1_];
    __shared__ float ps[4][U2_];
    const int b = blockIdx.x, tid = threadIdx.x;
    if (tid < 128) *(float4*)(hs + tid * 4) = *(const float4*)(hfin + (long)b * H_ + tid * 4);
    __syncthreads();
    float acc = b2[tid];
    #pragma unroll 8
    for (int k = 0; k < H_; ++k) acc += hs[k] * W2[(long)k * U1_ + tid];
    ys[tid] = fmaxf(acc, 0.f);
    __syncthreads();
    const int u2 = tid & 63, part = tid >> 6;
    float p = 0.f;
    #pragma unroll 8
    for (int k = part * 64; k < part * 64 + 64; ++k) p += ys[k] * W3[(long)k * U2_ + u2];
    ps[part][u2] = p;
    __syncthreads();
    if (tid < 64) {
        float lg = b3[tid] + ps[0][tid] + ps[1][tid] + ps[2][tid] + ps[3][tid];
        float m = lg;
        #pragma unroll
        for (int off = 32; off >= 1; off >>= 1) m = fmaxf(m, __shfl_xor(m, off, 64));
        float e = __expf(lg - m);
        float s = e;
        #pragma unroll
        for (int off = 32; off >= 1; off >>= 1) s += __shfl_xor(s, off, 64);
        out[(long)b * U2_ + tid] = e / s;
    }
}

extern "C" void kernel_launch(void* const* d_in, const int* in_sizes, int n_in,
                              void* d_out, int out_size, void* d_ws, size_t ws_size,
                              hipStream_t stream) {
    const int*   inp = (const int*)d_in[0];
    const float* emb = (const float*)d_in[1];
    const float* W   = (const float*)d_in[2];
    const float* U   = (const float*)d_in[3];
    const float* bb  = (const float*)d_in[4];
    const float* W2  = (const float*)d_in[5];
    const float* b2  = (const float*)d_in[6];
    const float* W3  = (const float*)d_in[7];
    const float* b3  = (const float*)d_in[8];

    char* ws = (char*)d_ws;
    short*        hfrag = (short*)ws;                                  // 2 * 256 KiB
    unsigned int* flags = (unsigned int*)(ws + 524288);                // 2 KiB (pad 4K)
    short*        xfrag = (short*)(ws + (1 << 20));                    // 16 MiB
    float*        hfin  = (float*)(ws + (1 << 20) + (long)T_ * XFRAG_SHORTS * 2); // 512 KiB

    // zero h(-1) double-buffer + per-WG flags (replay-deterministic)
    hipMemsetAsync(ws, 0, 524288 + 4096, stream);
    k_gather<<<256, 256, 0, stream>>>(inp, emb, xfrag);
    k_lstm<<<NWG, 256, 0, stream>>>(U, W, bb, xfrag, hfrag, flags, hfin);
    k_head<<<B_, 256, 0, stream>>>(hfin, W2, b2, W3, b3, (float*)d_out);
}